// Round 1
// baseline (380.200 us; speedup 1.0000x reference)
//
#include <hip/hip_runtime.h>

// Problem constants
#define NND 10000      // nodes
#define NED 160000     // edges (before self loops)
#define NET 170000     // edges incl self loops
#define MP  10112      // node rows padded to multiple of 128 (79*128)
#define DH  1024       // H*C hidden width
#define DIN 512
#define DOUT 512
#define CHUNK 128      // agg edge chunk

typedef unsigned short u16;
typedef __attribute__((ext_vector_type(8))) short short8_t;
typedef __attribute__((ext_vector_type(8))) unsigned short u16x8_t;
typedef __attribute__((ext_vector_type(4))) float f32x4_t;

__device__ __forceinline__ u16 f2bf(float f) {
  unsigned u = __float_as_uint(f);
  return (u16)((u + 0x7fffu + ((u >> 16) & 1u)) >> 16);
}
__device__ __forceinline__ float lrelu(float v) { return v > 0.f ? v : 0.2f * v; }

// ---------------- utility kernels ----------------

__global__ void k_zero32(int* __restrict__ p, int n) {
  int i = blockIdx.x * 256 + threadIdx.x;
  if (i < n) p[i] = 0;
}
__global__ void k_zero16(u16* __restrict__ p, int n) {
  int i = blockIdx.x * 256 + threadIdx.x;
  if (i < n) p[i] = 0;
}

// x [NND][DIN] f32 -> xb [MP][DIN] bf16 (pad rows zero)
__global__ void k_conv_x(const float* __restrict__ x, u16* __restrict__ xb) {
  int i = blockIdx.x * 256 + threadIdx.x;   // quad index
  const int total = MP * DIN / 4;
  if (i >= total) return;
  float4 v = make_float4(0.f, 0.f, 0.f, 0.f);
  if (i < NND * DIN / 4) v = ((const float4*)x)[i];
  ushort4 o;
  o.x = f2bf(v.x); o.y = f2bf(v.y); o.z = f2bf(v.z); o.w = f2bf(v.w);
  ((ushort4*)xb)[i] = o;
}

// W [K][Nt] f32 -> WT [Nt][K] bf16  (LDS tiled transpose)
__global__ void k_transpose_w(const float* __restrict__ W, u16* __restrict__ WT,
                              int K, int Nt) {
  __shared__ float s[32][33];
  int kt = blockIdx.y * 32, nt = blockIdx.x * 32;
  int tx = threadIdx.x, ty = threadIdx.y;   // (32,8)
#pragma unroll
  for (int i = 0; i < 32; i += 8)
    s[ty + i][tx] = W[(size_t)(kt + ty + i) * Nt + nt + tx];
  __syncthreads();
#pragma unroll
  for (int i = 0; i < 32; i += 8)
    WT[(size_t)(nt + ty + i) * K + kt + tx] = f2bf(s[tx][ty + i]);
}

// ---------------- CSR build ----------------

__global__ void k_count(const int* __restrict__ ei, int* __restrict__ indeg) {
  int e = blockIdx.x * 256 + threadIdx.x;
  if (e >= NET) return;
  int dst = (e < NED) ? ei[NED + e] : (e - NED);
  atomicAdd(&indeg[dst], 1);
}

__global__ void k_scan(const int* __restrict__ indeg, int* __restrict__ rowp) {
  __shared__ int sb[1024];
  __shared__ int carry;
  int t = threadIdx.x;
  if (t == 0) { carry = 0; rowp[0] = 0; }
  __syncthreads();
  for (int base = 0; base < NND; base += 1024) {
    int v = (base + t < NND) ? indeg[base + t] : 0;
    sb[t] = v;
    __syncthreads();
    for (int off = 1; off < 1024; off <<= 1) {
      int xx = (t >= off) ? sb[t - off] : 0;
      __syncthreads();
      sb[t] += xx;
      __syncthreads();
    }
    if (base + t < NND) rowp[base + t + 1] = carry + sb[t];
    __syncthreads();
    if (t == 0) carry += sb[1023];
    __syncthreads();
  }
}

__global__ void k_fill(const int* __restrict__ ei, const int* __restrict__ rowp,
                       int* __restrict__ cursor, int* __restrict__ colsrc) {
  int e = blockIdx.x * 256 + threadIdx.x;
  if (e >= NET) return;
  int src, dst;
  if (e < NED) { src = ei[e]; dst = ei[NED + e]; }
  else         { src = dst = e - NED; }
  int pos = rowp[dst] + atomicAdd(&cursor[dst], 1);
  colsrc[pos] = src;
}

// ---------------- GEMM: C[M][ldc] = A[M][KD] * BT[Nt][KD]^T (+bias) ----------------
// bf16 inputs, fp32 accum/output. 128x128 tile, BK=32, 4 waves, 16x16x32 MFMA.

template <int KD, bool HAS_BIAS, bool GUARD>
__global__ __launch_bounds__(256) void k_gemm(const u16* __restrict__ A,
                                              const u16* __restrict__ BT,
                                              float* __restrict__ C,
                                              const float* __restrict__ bias,
                                              int ldc, int mvalid) {
  __shared__ __align__(16) u16 As[128 * 32];
  __shared__ __align__(16) u16 Bs[128 * 32];
  const int tid = threadIdx.x;
  const int lane = tid & 63;
  const int w = tid >> 6;
  const int wr = w >> 1, wc = w & 1;
  const int l15 = lane & 15;
  const int kg = (lane >> 4) * 8;
  const int mt = blockIdx.y, nt = blockIdx.x;

  // staging geometry: thread covers flat bf16 elems [(i*256+tid)*8, +8)
  const int flat0 = tid * 8;
  const int row0 = flat0 >> 5, kk0 = flat0 & 31;
  const int flat1 = (256 + tid) * 8;
  const int row1 = flat1 >> 5, kk1 = flat1 & 31;

  const u16* Ab = A + (size_t)(mt * 128) * KD;
  const u16* Bb = BT + (size_t)(nt * 128) * KD;
  const u16* ga0 = Ab + row0 * KD + kk0;
  const u16* ga1 = Ab + row1 * KD + kk1;
  const u16* gb0 = Bb + row0 * KD + kk0;
  const u16* gb1 = Bb + row1 * KD + kk1;

  f32x4_t acc[4][4];
#pragma unroll
  for (int i = 0; i < 4; i++)
#pragma unroll
    for (int j = 0; j < 4; j++)
#pragma unroll
      for (int q = 0; q < 4; q++) acc[i][j][q] = 0.f;

  for (int kt = 0; kt < KD; kt += 32) {
    u16x8_t ra0 = *(const u16x8_t*)(ga0 + kt);
    u16x8_t ra1 = *(const u16x8_t*)(ga1 + kt);
    u16x8_t rb0 = *(const u16x8_t*)(gb0 + kt);
    u16x8_t rb1 = *(const u16x8_t*)(gb1 + kt);
    __syncthreads();   // previous iter's LDS reads done
    *(u16x8_t*)(As + flat0) = ra0;
    *(u16x8_t*)(As + flat1) = ra1;
    *(u16x8_t*)(Bs + flat0) = rb0;
    *(u16x8_t*)(Bs + flat1) = rb1;
    __syncthreads();
    short8_t af[4], bfr[4];
#pragma unroll
    for (int i = 0; i < 4; i++)
      af[i] = *(const short8_t*)(As + (wr * 64 + i * 16 + l15) * 32 + kg);
#pragma unroll
    for (int i = 0; i < 4; i++)
      bfr[i] = *(const short8_t*)(Bs + (wc * 64 + i * 16 + l15) * 32 + kg);
#pragma unroll
    for (int i = 0; i < 4; i++)
#pragma unroll
      for (int j = 0; j < 4; j++)
        acc[i][j] = __builtin_amdgcn_mfma_f32_16x16x32_bf16(af[i], bfr[j], acc[i][j], 0, 0, 0);
  }

  const int rbase = mt * 128 + wr * 64 + (lane >> 4) * 4;
  const int cbase = nt * 128 + wc * 64 + l15;
#pragma unroll
  for (int i = 0; i < 4; i++) {
#pragma unroll
    for (int j = 0; j < 4; j++) {
#pragma unroll
      for (int q = 0; q < 4; q++) {
        int r = rbase + i * 16 + q;
        int c = cbase + j * 16;
        if (!GUARD || r < mvalid) {
          float v = acc[i][j][q];
          if (HAS_BIAS) v += bias[c];
          C[(size_t)r * ldc + c] = v;
        }
      }
    }
  }
}

// ---------------- attention logits: al_s/al_d [NND][4] ----------------

__global__ __launch_bounds__(256) void k_al(const float* __restrict__ hproj,
                                            const float* __restrict__ a_src,
                                            const float* __restrict__ a_dst,
                                            float* __restrict__ al_s,
                                            float* __restrict__ al_d) {
  int n = blockIdx.x, t = threadIdx.x;
  float4 hv = ((const float4*)(hproj + (size_t)n * DH))[t];
  float4 as = ((const float4*)a_src)[t];
  float4 ad = ((const float4*)a_dst)[t];
  float ps = hv.x * as.x + hv.y * as.y + hv.z * as.z + hv.w * as.w;
  float pd = hv.x * ad.x + hv.y * ad.y + hv.z * ad.z + hv.w * ad.w;
#pragma unroll
  for (int off = 32; off; off >>= 1) {
    ps += __shfl_xor(ps, off);
    pd += __shfl_xor(pd, off);
  }
  if ((t & 63) == 0) {
    int h = t >> 6;
    al_s[n * 4 + h] = ps;
    al_d[n * 4 + h] = pd;
  }
}

// ---------------- segment softmax + weighted aggregation ----------------
// one block per dst node; out = relu(sum(alpha*h[src]) + bias) as bf16

__global__ __launch_bounds__(256) void k_agg(const float* __restrict__ hproj,
                                             const float* __restrict__ al_s,
                                             const float* __restrict__ al_d,
                                             const int* __restrict__ rowp,
                                             const int* __restrict__ colsrc,
                                             const float* __restrict__ bias,
                                             u16* __restrict__ outb) {
  __shared__ int csrc[CHUNK];
  __shared__ float cw[CHUNK * 4];
  __shared__ float smax[4][4];
  __shared__ float sbmax[4];
  const int n = blockIdx.x, t = threadIdx.x;
  const int wv = t >> 6, ln = t & 63;
  const int hh = t >> 6;   // head owning this thread's 4 channels
  const int beg = rowp[n], end = rowp[n + 1];
  const float4 ad = ((const float4*)al_d)[n];

  // pass A: per-head max of leaky_relu(al_s[src]+al_d[n])
  float m0 = -1e30f, m1 = -1e30f, m2 = -1e30f, m3 = -1e30f;
  for (int e = beg + t; e < end; e += 256) {
    int s = colsrc[e];
    float4 as = ((const float4*)al_s)[s];
    m0 = fmaxf(m0, lrelu(as.x + ad.x));
    m1 = fmaxf(m1, lrelu(as.y + ad.y));
    m2 = fmaxf(m2, lrelu(as.z + ad.z));
    m3 = fmaxf(m3, lrelu(as.w + ad.w));
  }
#pragma unroll
  for (int off = 32; off; off >>= 1) {
    m0 = fmaxf(m0, __shfl_xor(m0, off));
    m1 = fmaxf(m1, __shfl_xor(m1, off));
    m2 = fmaxf(m2, __shfl_xor(m2, off));
    m3 = fmaxf(m3, __shfl_xor(m3, off));
  }
  if (ln == 0) { smax[0][wv] = m0; smax[1][wv] = m1; smax[2][wv] = m2; smax[3][wv] = m3; }
  __syncthreads();
  if (t < 4)
    sbmax[t] = fmaxf(fmaxf(smax[t][0], smax[t][1]), fmaxf(smax[t][2], smax[t][3]));
  __syncthreads();
  const float bm0 = sbmax[0], bm1 = sbmax[1], bm2 = sbmax[2], bm3 = sbmax[3];

  // pass B: chunked accumulate of sum(w*h) and sum(w)
  float ax = 0.f, ay = 0.f, az = 0.f, aw = 0.f;
  float dsum = 0.f;
  for (int cs = beg; cs < end; cs += CHUNK) {
    int m = end - cs; if (m > CHUNK) m = CHUNK;
    __syncthreads();   // protect LDS from previous chunk readers
    if (t < m) {
      int s = colsrc[cs + t];
      csrc[t] = s;
      float4 as = ((const float4*)al_s)[s];
      float4 wv4;
      wv4.x = __expf(lrelu(as.x + ad.x) - bm0);
      wv4.y = __expf(lrelu(as.y + ad.y) - bm1);
      wv4.z = __expf(lrelu(as.z + ad.z) - bm2);
      wv4.w = __expf(lrelu(as.w + ad.w) - bm3);
      ((float4*)cw)[t] = wv4;
    }
    __syncthreads();
    for (int i = 0; i < m; i++) {
      int s = csrc[i];
      float wgt = cw[i * 4 + hh];
      float4 hv = ((const float4*)(hproj + (size_t)s * DH))[t];
      ax += hv.x * wgt; ay += hv.y * wgt; az += hv.z * wgt; aw += hv.w * wgt;
      dsum += wgt;
    }
  }
  const float inv = 1.f / dsum;
  float4 bv = ((const float4*)bias)[t];
  float o0 = fmaxf(ax * inv + bv.x, 0.f);
  float o1 = fmaxf(ay * inv + bv.y, 0.f);
  float o2 = fmaxf(az * inv + bv.z, 0.f);
  float o3 = fmaxf(aw * inv + bv.w, 0.f);
  ushort4 ob;
  ob.x = f2bf(o0); ob.y = f2bf(o1); ob.z = f2bf(o2); ob.w = f2bf(o3);
  ((ushort4*)(outb + (size_t)n * DH))[t] = ob;
}

// ---------------- launcher ----------------

extern "C" void kernel_launch(void* const* d_in, const int* in_sizes, int n_in,
                              void* d_out, int out_size, void* d_ws, size_t ws_size,
                              hipStream_t stream) {
  const float* x   = (const float*)d_in[0];
  const int*   ei  = (const int*)d_in[1];
  const float* W1  = (const float*)d_in[2];
  const float* as1 = (const float*)d_in[3];
  const float* ad1 = (const float*)d_in[4];
  const float* b1  = (const float*)d_in[5];
  const float* W2  = (const float*)d_in[6];
  const float* as2 = (const float*)d_in[7];
  const float* ad2 = (const float*)d_in[8];
  const float* b2  = (const float*)d_in[9];
  const float* Wfc = (const float*)d_in[10];
  const float* bfc = (const float*)d_in[11];
  float* out = (float*)d_out;
  (void)in_sizes; (void)n_in; (void)out_size; (void)ws_size;

  // workspace carve (~99 MB)
  char* p = (char*)d_ws;
  auto carve = [&](size_t bytes) -> char* {
    char* r = p; p += (bytes + 255) & ~(size_t)255; return r;
  };
  u16*   xb    = (u16*)  carve((size_t)MP * DIN * 2);
  u16*   w1t   = (u16*)  carve((size_t)DH * DIN * 2);    // [1024][512]
  u16*   w2t   = (u16*)  carve((size_t)DH * DH * 2);     // [1024][1024]
  u16*   wft   = (u16*)  carve((size_t)DOUT * DH * 2);   // [512][1024]
  float* hproj = (float*)carve((size_t)MP * DH * 4);
  u16*   hb    = (u16*)  carve((size_t)MP * DH * 2);
  u16*   h2b   = (u16*)  carve((size_t)MP * DH * 2);
  float* als   = (float*)carve((size_t)NND * 4 * 4);
  float* ald   = (float*)carve((size_t)NND * 4 * 4);
  int*   indeg = (int*)  carve((size_t)NND * 4);
  int*   rowp  = (int*)  carve((size_t)(NND + 1) * 4);
  int*   cursor= (int*)  carve((size_t)NND * 4);
  int*   colsrc= (int*)  carve((size_t)NET * 4);

  // prep: zeros, conversions, CSR
  k_zero32<<<(NND + 255) / 256, 256, 0, stream>>>(indeg, NND);
  k_zero32<<<(NND + 255) / 256, 256, 0, stream>>>(cursor, NND);
  k_zero16<<<((MP - NND) * DH + 255) / 256, 256, 0, stream>>>(hb + (size_t)NND * DH, (MP - NND) * DH);
  k_zero16<<<((MP - NND) * DH + 255) / 256, 256, 0, stream>>>(h2b + (size_t)NND * DH, (MP - NND) * DH);
  k_conv_x<<<(MP * DIN / 4 + 255) / 256, 256, 0, stream>>>(x, xb);
  k_transpose_w<<<dim3(DH / 32, DIN / 32), dim3(32, 8), 0, stream>>>(W1, w1t, DIN, DH);
  k_transpose_w<<<dim3(DH / 32, DH / 32), dim3(32, 8), 0, stream>>>(W2, w2t, DH, DH);
  k_transpose_w<<<dim3(DOUT / 32, DH / 32), dim3(32, 8), 0, stream>>>(Wfc, wft, DH, DOUT);
  k_count<<<(NET + 255) / 256, 256, 0, stream>>>(ei, indeg);
  k_scan<<<1, 1024, 0, stream>>>(indeg, rowp);
  k_fill<<<(NET + 255) / 256, 256, 0, stream>>>(ei, rowp, cursor, colsrc);

  // layer 1
  k_gemm<DIN, false, false><<<dim3(DH / 128, MP / 128), 256, 0, stream>>>(xb, w1t, hproj, nullptr, DH, MP);
  k_al<<<NND, 256, 0, stream>>>(hproj, as1, ad1, als, ald);
  k_agg<<<NND, 256, 0, stream>>>(hproj, als, ald, rowp, colsrc, b1, hb);

  // layer 2
  k_gemm<DH, false, false><<<dim3(DH / 128, MP / 128), 256, 0, stream>>>(hb, w2t, hproj, nullptr, DH, MP);
  k_al<<<NND, 256, 0, stream>>>(hproj, as2, ad2, als, ald);
  k_agg<<<NND, 256, 0, stream>>>(hproj, als, ald, rowp, colsrc, b2, h2b);

  // FC
  k_gemm<DH, true, true><<<dim3(DOUT / 128, MP / 128), 256, 0, stream>>>(h2b, wft, out, bfc, DOUT, NND);
}

// Round 2
// 264.986 us; speedup vs baseline: 1.4348x; 1.4348x over previous
//
#include <hip/hip_runtime.h>

// Problem constants
#define NND 10000      // nodes
#define NED 160000     // edges (before self loops)
#define NET 170000     // edges incl self loops
#define MP  10112      // node rows padded to multiple of 128 (79*128)
#define DH  1024       // H*C hidden width
#define DIN 512
#define DOUT 512
#define CHUNK 128      // agg edge chunk

typedef unsigned short u16;
typedef __attribute__((ext_vector_type(8))) short short8_t;
typedef __attribute__((ext_vector_type(4))) float f32x4_t;

__device__ __forceinline__ u16 f2bf(float f) {
  unsigned u = __float_as_uint(f);
  return (u16)((u + 0x7fffu + ((u >> 16) & 1u)) >> 16);
}
__device__ __forceinline__ float bf2f(u16 b) {
  return __uint_as_float(((unsigned)b) << 16);
}
__device__ __forceinline__ float lrelu(float v) { return v > 0.f ? v : 0.2f * v; }

// async global->LDS, 16B per lane. LDS dest must be linear (uniform base + lane*16).
__device__ __forceinline__ void gl_lds16(const void* g, void* l) {
  __builtin_amdgcn_global_load_lds(
      (const __attribute__((address_space(1))) unsigned int*)g,
      (__attribute__((address_space(3))) unsigned int*)l, 16, 0, 0);
}

// ---------------- utility kernels ----------------

__global__ void k_zero32(int* __restrict__ p, int n) {
  int i = blockIdx.x * 256 + threadIdx.x;
  if (i < n) p[i] = 0;
}
__global__ void k_zero16(u16* __restrict__ p, int n) {
  int i = blockIdx.x * 256 + threadIdx.x;
  if (i < n) p[i] = 0;
}

// x [NND][DIN] f32 -> xb [MP][DIN] bf16 (pad rows zero)
__global__ void k_conv_x(const float* __restrict__ x, u16* __restrict__ xb) {
  int i = blockIdx.x * 256 + threadIdx.x;   // quad index
  const int total = MP * DIN / 4;
  if (i >= total) return;
  float4 v = make_float4(0.f, 0.f, 0.f, 0.f);
  if (i < NND * DIN / 4) v = ((const float4*)x)[i];
  ushort4 o;
  o.x = f2bf(v.x); o.y = f2bf(v.y); o.z = f2bf(v.z); o.w = f2bf(v.w);
  ((ushort4*)xb)[i] = o;
}

// W [K][Nt] f32 -> WT [Nt][K] bf16  (LDS tiled transpose)
__global__ void k_transpose_w(const float* __restrict__ W, u16* __restrict__ WT,
                              int K, int Nt) {
  __shared__ float s[32][33];
  int kt = blockIdx.y * 32, nt = blockIdx.x * 32;
  int tx = threadIdx.x, ty = threadIdx.y;   // (32,8)
#pragma unroll
  for (int i = 0; i < 32; i += 8)
    s[ty + i][tx] = W[(size_t)(kt + ty + i) * Nt + nt + tx];
  __syncthreads();
#pragma unroll
  for (int i = 0; i < 32; i += 8)
    WT[(size_t)(nt + ty + i) * K + kt + tx] = f2bf(s[tx][ty + i]);
}

// ---------------- CSR build ----------------

__global__ void k_count(const int* __restrict__ ei, int* __restrict__ indeg) {
  int e = blockIdx.x * 256 + threadIdx.x;
  if (e >= NET) return;
  int dst = (e < NED) ? ei[NED + e] : (e - NED);
  atomicAdd(&indeg[dst], 1);
}

__global__ void k_scan(const int* __restrict__ indeg, int* __restrict__ rowp) {
  __shared__ int sb[1024];
  __shared__ int carry;
  int t = threadIdx.x;
  if (t == 0) { carry = 0; rowp[0] = 0; }
  __syncthreads();
  for (int base = 0; base < NND; base += 1024) {
    int v = (base + t < NND) ? indeg[base + t] : 0;
    sb[t] = v;
    __syncthreads();
    for (int off = 1; off < 1024; off <<= 1) {
      int xx = (t >= off) ? sb[t - off] : 0;
      __syncthreads();
      sb[t] += xx;
      __syncthreads();
    }
    if (base + t < NND) rowp[base + t + 1] = carry + sb[t];
    __syncthreads();
    if (t == 0) carry += sb[1023];
    __syncthreads();
  }
}

__global__ void k_fill(const int* __restrict__ ei, const int* __restrict__ rowp,
                       int* __restrict__ cursor, int* __restrict__ colsrc) {
  int e = blockIdx.x * 256 + threadIdx.x;
  if (e >= NET) return;
  int src, dst;
  if (e < NED) { src = ei[e]; dst = ei[NED + e]; }
  else         { src = dst = e - NED; }
  int pos = rowp[dst] + atomicAdd(&cursor[dst], 1);
  colsrc[pos] = src;
}

// ---------------- GEMM: C[M][ldc] = A[M][KD] * BT[Nt][KD]^T (+bias) ----------------
// bf16 inputs, fp32 accum. Output bf16 (OUTBF) or fp32. 128x128 tile, BK=32,
// 4 waves, 16x16x32 MFMA, global_load_lds width-16 staging (m97 structure).

template <int KD, bool HAS_BIAS, bool GUARD, bool OUTBF>
__global__ __launch_bounds__(256) void k_gemm(const u16* __restrict__ A,
                                              const u16* __restrict__ BT,
                                              float* __restrict__ Cf,
                                              u16* __restrict__ Cb,
                                              const float* __restrict__ bias,
                                              int ldc, int mvalid) {
  __shared__ __align__(16) u16 As[128 * 32];
  __shared__ __align__(16) u16 Bs[128 * 32];
  const int tid = threadIdx.x;
  const int lane = tid & 63;
  const int w = tid >> 6;
  const int wr = w >> 1, wc = w & 1;
  const int l15 = lane & 15;
  const int kg = (lane >> 4) * 8;
  const int mt = blockIdx.y, nt = blockIdx.x;

  // staging geometry: thread covers flat bf16 elems [(i*256+tid)*8, +8)
  const int flat0 = tid * 8;              // LDS elem offset, chunk 0
  const int row0 = flat0 >> 5, kk0 = flat0 & 31;
  const int row1 = 64 + row0;             // chunk 1: flat1 = 2048 + flat0

  const u16* Ab = A + (size_t)(mt * 128) * KD;
  const u16* Bb = BT + (size_t)(nt * 128) * KD;
  const u16* ga0 = Ab + row0 * KD + kk0;
  const u16* ga1 = Ab + row1 * KD + kk0;
  const u16* gb0 = Bb + row0 * KD + kk0;
  const u16* gb1 = Bb + row1 * KD + kk0;
  u16* lA0 = As + flat0;
  u16* lA1 = As + 2048 + flat0;
  u16* lB0 = Bs + flat0;
  u16* lB1 = Bs + 2048 + flat0;

  f32x4_t acc[4][4];
#pragma unroll
  for (int i = 0; i < 4; i++)
#pragma unroll
    for (int j = 0; j < 4; j++)
#pragma unroll
      for (int q = 0; q < 4; q++) acc[i][j][q] = 0.f;

  for (int kt = 0; kt < KD; kt += 32) {
    __syncthreads();   // previous iter's LDS reads done before overwrite
    gl_lds16(ga0 + kt, lA0);
    gl_lds16(ga1 + kt, lA1);
    gl_lds16(gb0 + kt, lB0);
    gl_lds16(gb1 + kt, lB1);
    __syncthreads();   // compiler drains vmcnt(0) before barrier -> LDS valid
    short8_t af[4], bfr[4];
#pragma unroll
    for (int i = 0; i < 4; i++)
      af[i] = *(const short8_t*)(As + (wr * 64 + i * 16 + l15) * 32 + kg);
#pragma unroll
    for (int i = 0; i < 4; i++)
      bfr[i] = *(const short8_t*)(Bs + (wc * 64 + i * 16 + l15) * 32 + kg);
#pragma unroll
    for (int i = 0; i < 4; i++)
#pragma unroll
      for (int j = 0; j < 4; j++)
        acc[i][j] = __builtin_amdgcn_mfma_f32_16x16x32_bf16(af[i], bfr[j], acc[i][j], 0, 0, 0);
  }

  const int rbase = mt * 128 + wr * 64 + (lane >> 4) * 4;
  const int cbase = nt * 128 + wc * 64 + l15;
#pragma unroll
  for (int i = 0; i < 4; i++) {
#pragma unroll
    for (int j = 0; j < 4; j++) {
#pragma unroll
      for (int q = 0; q < 4; q++) {
        int r = rbase + i * 16 + q;
        int c = cbase + j * 16;
        if (!GUARD || r < mvalid) {
          float v = acc[i][j][q];
          if (HAS_BIAS) v += bias[c];
          if (OUTBF) Cb[(size_t)r * ldc + c] = f2bf(v);
          else       Cf[(size_t)r * ldc + c] = v;
        }
      }
    }
  }
}

// ---------------- attention logits: al_s/al_d [NND][4] (bf16 hproj) ----------------

__global__ __launch_bounds__(256) void k_al(const u16* __restrict__ hprojb,
                                            const float* __restrict__ a_src,
                                            const float* __restrict__ a_dst,
                                            float* __restrict__ al_s,
                                            float* __restrict__ al_d) {
  int n = blockIdx.x, t = threadIdx.x;
  ushort4 hq = ((const ushort4*)(hprojb + (size_t)n * DH))[t];
  float4 as = ((const float4*)a_src)[t];
  float4 ad = ((const float4*)a_dst)[t];
  float hx = bf2f(hq.x), hy = bf2f(hq.y), hz = bf2f(hq.z), hw = bf2f(hq.w);
  float ps = hx * as.x + hy * as.y + hz * as.z + hw * as.w;
  float pd = hx * ad.x + hy * ad.y + hz * ad.z + hw * ad.w;
#pragma unroll
  for (int off = 32; off; off >>= 1) {
    ps += __shfl_xor(ps, off);
    pd += __shfl_xor(pd, off);
  }
  if ((t & 63) == 0) {
    int h = t >> 6;
    al_s[n * 4 + h] = ps;
    al_d[n * 4 + h] = pd;
  }
}

// ---------------- segment softmax + weighted aggregation ----------------
// one block per dst node; gathers bf16 h rows; out = relu(sum(alpha*h[src])+bias) bf16

__global__ __launch_bounds__(256) void k_agg(const u16* __restrict__ hprojb,
                                             const float* __restrict__ al_s,
                                             const float* __restrict__ al_d,
                                             const int* __restrict__ rowp,
                                             const int* __restrict__ colsrc,
                                             const float* __restrict__ bias,
                                             u16* __restrict__ outb) {
  __shared__ int csrc[CHUNK];
  __shared__ float cw[CHUNK * 4];
  __shared__ float smax[4][4];
  __shared__ float sbmax[4];
  const int n = blockIdx.x, t = threadIdx.x;
  const int wv = t >> 6, ln = t & 63;
  const int hh = t >> 6;   // head owning this thread's 4 channels
  const int beg = rowp[n], end = rowp[n + 1];
  const float4 ad = ((const float4*)al_d)[n];

  // pass A: per-head max of leaky_relu(al_s[src]+al_d[n])
  float m0 = -1e30f, m1 = -1e30f, m2 = -1e30f, m3 = -1e30f;
  for (int e = beg + t; e < end; e += 256) {
    int s = colsrc[e];
    float4 as = ((const float4*)al_s)[s];
    m0 = fmaxf(m0, lrelu(as.x + ad.x));
    m1 = fmaxf(m1, lrelu(as.y + ad.y));
    m2 = fmaxf(m2, lrelu(as.z + ad.z));
    m3 = fmaxf(m3, lrelu(as.w + ad.w));
  }
#pragma unroll
  for (int off = 32; off; off >>= 1) {
    m0 = fmaxf(m0, __shfl_xor(m0, off));
    m1 = fmaxf(m1, __shfl_xor(m1, off));
    m2 = fmaxf(m2, __shfl_xor(m2, off));
    m3 = fmaxf(m3, __shfl_xor(m3, off));
  }
  if (ln == 0) { smax[0][wv] = m0; smax[1][wv] = m1; smax[2][wv] = m2; smax[3][wv] = m3; }
  __syncthreads();
  if (t < 4)
    sbmax[t] = fmaxf(fmaxf(smax[t][0], smax[t][1]), fmaxf(smax[t][2], smax[t][3]));
  __syncthreads();
  const float bm0 = sbmax[0], bm1 = sbmax[1], bm2 = sbmax[2], bm3 = sbmax[3];

  // pass B: chunked accumulate of sum(w*h) and sum(w); h rows are bf16 (2KB)
  float ax = 0.f, ay = 0.f, az = 0.f, aw = 0.f;
  float dsum = 0.f;
  for (int cs = beg; cs < end; cs += CHUNK) {
    int m = end - cs; if (m > CHUNK) m = CHUNK;
    __syncthreads();   // protect LDS from previous chunk readers
    if (t < m) {
      int s = colsrc[cs + t];
      csrc[t] = s;
      float4 as = ((const float4*)al_s)[s];
      float4 wv4;
      wv4.x = __expf(lrelu(as.x + ad.x) - bm0);
      wv4.y = __expf(lrelu(as.y + ad.y) - bm1);
      wv4.z = __expf(lrelu(as.z + ad.z) - bm2);
      wv4.w = __expf(lrelu(as.w + ad.w) - bm3);
      ((float4*)cw)[t] = wv4;
    }
    __syncthreads();
    for (int i = 0; i < m; i++) {
      int s = csrc[i];
      float wgt = cw[i * 4 + hh];
      ushort4 hq = ((const ushort4*)(hprojb + (size_t)s * DH))[t];
      ax += bf2f(hq.x) * wgt; ay += bf2f(hq.y) * wgt;
      az += bf2f(hq.z) * wgt; aw += bf2f(hq.w) * wgt;
      dsum += wgt;
    }
  }
  const float inv = 1.f / dsum;
  float4 bv = ((const float4*)bias)[t];
  float o0 = fmaxf(ax * inv + bv.x, 0.f);
  float o1 = fmaxf(ay * inv + bv.y, 0.f);
  float o2 = fmaxf(az * inv + bv.z, 0.f);
  float o3 = fmaxf(aw * inv + bv.w, 0.f);
  ushort4 ob;
  ob.x = f2bf(o0); ob.y = f2bf(o1); ob.z = f2bf(o2); ob.w = f2bf(o3);
  ((ushort4*)(outb + (size_t)n * DH))[t] = ob;
}

// ---------------- launcher ----------------

extern "C" void kernel_launch(void* const* d_in, const int* in_sizes, int n_in,
                              void* d_out, int out_size, void* d_ws, size_t ws_size,
                              hipStream_t stream) {
  const float* x   = (const float*)d_in[0];
  const int*   ei  = (const int*)d_in[1];
  const float* W1  = (const float*)d_in[2];
  const float* as1 = (const float*)d_in[3];
  const float* ad1 = (const float*)d_in[4];
  const float* b1  = (const float*)d_in[5];
  const float* W2  = (const float*)d_in[6];
  const float* as2 = (const float*)d_in[7];
  const float* ad2 = (const float*)d_in[8];
  const float* b2  = (const float*)d_in[9];
  const float* Wfc = (const float*)d_in[10];
  const float* bfc = (const float*)d_in[11];
  float* out = (float*)d_out;
  (void)in_sizes; (void)n_in; (void)out_size; (void)ws_size;

  // workspace carve
  char* p = (char*)d_ws;
  auto carve = [&](size_t bytes) -> char* {
    char* r = p; p += (bytes + 255) & ~(size_t)255; return r;
  };
  u16*   xb     = (u16*)  carve((size_t)MP * DIN * 2);
  u16*   w1t    = (u16*)  carve((size_t)DH * DIN * 2);    // [1024][512]
  u16*   w2t    = (u16*)  carve((size_t)DH * DH * 2);     // [1024][1024]
  u16*   wft    = (u16*)  carve((size_t)DOUT * DH * 2);   // [512][1024]
  u16*   hprojb = (u16*)  carve((size_t)MP * DH * 2);     // bf16 projection
  u16*   hb     = (u16*)  carve((size_t)MP * DH * 2);
  u16*   h2b    = (u16*)  carve((size_t)MP * DH * 2);
  float* als    = (float*)carve((size_t)NND * 4 * 4);
  float* ald    = (float*)carve((size_t)NND * 4 * 4);
  int*   indeg  = (int*)  carve((size_t)NND * 4);
  int*   rowp   = (int*)  carve((size_t)(NND + 1) * 4);
  int*   cursor = (int*)  carve((size_t)NND * 4);
  int*   colsrc = (int*)  carve((size_t)NET * 4);

  // prep: zeros, conversions, CSR
  k_zero32<<<(NND + 255) / 256, 256, 0, stream>>>(indeg, NND);
  k_zero32<<<(NND + 255) / 256, 256, 0, stream>>>(cursor, NND);
  k_zero16<<<((MP - NND) * DH + 255) / 256, 256, 0, stream>>>(hb + (size_t)NND * DH, (MP - NND) * DH);
  k_zero16<<<((MP - NND) * DH + 255) / 256, 256, 0, stream>>>(h2b + (size_t)NND * DH, (MP - NND) * DH);
  k_conv_x<<<(MP * DIN / 4 + 255) / 256, 256, 0, stream>>>(x, xb);
  k_transpose_w<<<dim3(DH / 32, DIN / 32), dim3(32, 8), 0, stream>>>(W1, w1t, DIN, DH);
  k_transpose_w<<<dim3(DH / 32, DH / 32), dim3(32, 8), 0, stream>>>(W2, w2t, DH, DH);
  k_transpose_w<<<dim3(DOUT / 32, DH / 32), dim3(32, 8), 0, stream>>>(Wfc, wft, DH, DOUT);
  k_count<<<(NET + 255) / 256, 256, 0, stream>>>(ei, indeg);
  k_scan<<<1, 1024, 0, stream>>>(indeg, rowp);
  k_fill<<<(NET + 255) / 256, 256, 0, stream>>>(ei, rowp, cursor, colsrc);

  // layer 1
  k_gemm<DIN, false, false, true><<<dim3(DH / 128, MP / 128), 256, 0, stream>>>(xb, w1t, nullptr, hprojb, nullptr, DH, MP);
  k_al<<<NND, 256, 0, stream>>>(hprojb, as1, ad1, als, ald);
  k_agg<<<NND, 256, 0, stream>>>(hprojb, als, ald, rowp, colsrc, b1, hb);

  // layer 2
  k_gemm<DH, false, false, true><<<dim3(DH / 128, MP / 128), 256, 0, stream>>>(hb, w2t, nullptr, hprojb, nullptr, DH, MP);
  k_al<<<NND, 256, 0, stream>>>(hprojb, as2, ad2, als, ald);
  k_agg<<<NND, 256, 0, stream>>>(hprojb, als, ald, rowp, colsrc, b2, h2b);

  // FC
  k_gemm<DH, true, true, false><<<dim3(DOUT / 128, MP / 128), 256, 0, stream>>>(h2b, wft, out, nullptr, bfc, DOUT, NND);
}

// Round 3
// 244.294 us; speedup vs baseline: 1.5563x; 1.0847x over previous
//
#include <hip/hip_runtime.h>

// Problem constants
#define NND 10000      // nodes
#define NED 160000     // edges (before self loops)
#define NET 170000     // edges incl self loops
#define MP  10112      // node rows padded to multiple of 128 (79*128)
#define DH  1024       // H*C hidden width
#define DIN 512
#define DOUT 512
#define CHUNK 128      // agg edge chunk

typedef unsigned short u16;
typedef __attribute__((ext_vector_type(8))) short short8_t;
typedef __attribute__((ext_vector_type(4))) float f32x4_t;

__device__ __forceinline__ u16 f2bf(float f) {
  unsigned u = __float_as_uint(f);
  return (u16)((u + 0x7fffu + ((u >> 16) & 1u)) >> 16);
}
__device__ __forceinline__ float bf2f(u16 b) {
  return __uint_as_float(((unsigned)b) << 16);
}
__device__ __forceinline__ float bflo(unsigned u) { return __uint_as_float(u << 16); }
__device__ __forceinline__ float bfhi(unsigned u) { return __uint_as_float(u & 0xffff0000u); }
__device__ __forceinline__ float lrelu(float v) { return v > 0.f ? v : 0.2f * v; }

// async global->LDS, 16B per lane. LDS dest must be linear (uniform base + lane*16).
__device__ __forceinline__ void gl_lds16(const void* g, void* l) {
  __builtin_amdgcn_global_load_lds(
      (const __attribute__((address_space(1))) unsigned int*)g,
      (__attribute__((address_space(3))) unsigned int*)l, 16, 0, 0);
}

// ---------------- merged prep: zero indeg/cursor + pad rows of hb/h2b ----------------

__global__ void k_prep0(int* __restrict__ indeg, int* __restrict__ cursor,
                        u16* __restrict__ hbp, u16* __restrict__ h2bp) {
  int i = blockIdx.x * 256 + threadIdx.x;
  if (i < NND) { indeg[i] = 0; cursor[i] = 0; }
  // pad region: (MP-NND)*DH u16 = 114688 -> 14336 uint4 writes per array
  const uint4 z = make_uint4(0, 0, 0, 0);
  if (i < (MP - NND) * DH / 8) {
    ((uint4*)hbp)[i] = z;
    ((uint4*)h2bp)[i] = z;
  }
}

// x [NND][DIN] f32 -> xb [MP][DIN] bf16 (pad rows zero)
__global__ void k_conv_x(const float* __restrict__ x, u16* __restrict__ xb) {
  int i = blockIdx.x * 256 + threadIdx.x;   // quad index
  const int total = MP * DIN / 4;
  if (i >= total) return;
  float4 v = make_float4(0.f, 0.f, 0.f, 0.f);
  if (i < NND * DIN / 4) v = ((const float4*)x)[i];
  ushort4 o;
  o.x = f2bf(v.x); o.y = f2bf(v.y); o.z = f2bf(v.z); o.w = f2bf(v.w);
  ((ushort4*)xb)[i] = o;
}

// W [K][Nt] f32 -> WT [Nt][K] bf16  (LDS tiled transpose)
__global__ void k_transpose_w(const float* __restrict__ W, u16* __restrict__ WT,
                              int K, int Nt) {
  __shared__ float s[32][33];
  int kt = blockIdx.y * 32, nt = blockIdx.x * 32;
  int tx = threadIdx.x, ty = threadIdx.y;   // (32,8)
#pragma unroll
  for (int i = 0; i < 32; i += 8)
    s[ty + i][tx] = W[(size_t)(kt + ty + i) * Nt + nt + tx];
  __syncthreads();
#pragma unroll
  for (int i = 0; i < 32; i += 8)
    WT[(size_t)(nt + ty + i) * K + kt + tx] = f2bf(s[tx][ty + i]);
}

// ---------------- CSR build ----------------

__global__ void k_count(const int* __restrict__ ei, int* __restrict__ indeg) {
  int e = blockIdx.x * 256 + threadIdx.x;
  if (e >= NET) return;
  int dst = (e < NED) ? ei[NED + e] : (e - NED);
  atomicAdd(&indeg[dst], 1);
}

// wave-shuffle inclusive scan, 1024 threads, 1 block
__global__ void k_scan(const int* __restrict__ indeg, int* __restrict__ rowp) {
  __shared__ int wsum[16];
  __shared__ int carry_s;
  const int t = threadIdx.x, wv = t >> 6, ln = t & 63;
  if (t == 0) { carry_s = 0; rowp[0] = 0; }
  __syncthreads();
  for (int base = 0; base < NND; base += 1024) {
    int v = (base + t < NND) ? indeg[base + t] : 0;
    int sc = v;
#pragma unroll
    for (int off = 1; off < 64; off <<= 1) {
      int xx = __shfl_up(sc, off);
      if (ln >= off) sc += xx;
    }
    if (ln == 63) wsum[wv] = sc;
    __syncthreads();
    if (t < 16) {
      int ws = wsum[t];
#pragma unroll
      for (int off = 1; off < 16; off <<= 1) {
        int xx = __shfl_up(ws, off);
        if (ln >= off) ws += xx;
      }
      wsum[t] = ws;
    }
    __syncthreads();
    int add = carry_s + (wv ? wsum[wv - 1] : 0);
    if (base + t < NND) rowp[base + t + 1] = sc + add;
    int tot = wsum[15];
    __syncthreads();
    if (t == 0) carry_s += tot;
    __syncthreads();
  }
}

__global__ void k_fill(const int* __restrict__ ei, const int* __restrict__ rowp,
                       int* __restrict__ cursor, int* __restrict__ colsrc) {
  int e = blockIdx.x * 256 + threadIdx.x;
  if (e >= NET) return;
  int src, dst;
  if (e < NED) { src = ei[e]; dst = ei[NED + e]; }
  else         { src = dst = e - NED; }
  int pos = rowp[dst] + atomicAdd(&cursor[dst], 1);
  colsrc[pos] = src;
}

// ---------------- GEMM: C[M][ldc] = A[M][KD] * BT[Nt][KD]^T (+bias) ----------------
// bf16 inputs, fp32 accum. Output bf16 (OUTBF) or fp32. 128x128 tile, BK=32,
// 4 waves, 16x16x32 MFMA, global_load_lds width-16 staging, XCD-chunked swizzle.

template <int KD, int GX, bool HAS_BIAS, bool GUARD, bool OUTBF>
__global__ __launch_bounds__(256) void k_gemm(const u16* __restrict__ A,
                                              const u16* __restrict__ BT,
                                              float* __restrict__ Cf,
                                              u16* __restrict__ Cb,
                                              const float* __restrict__ bias,
                                              int ldc, int mvalid) {
  __shared__ __align__(16) u16 As[128 * 32];
  __shared__ __align__(16) u16 Bs[128 * 32];
  const int tid = threadIdx.x;
  const int lane = tid & 63;
  const int w = tid >> 6;
  const int wr = w >> 1, wc = w & 1;
  const int l15 = lane & 15;
  const int kg = (lane >> 4) * 8;

  // XCD-chunked bijective swizzle (m204): xcd = bid%8 gets a contiguous wk chunk
  const int nwg = GX * gridDim.y;
  const int bid = blockIdx.y * GX + blockIdx.x;
  const int q = nwg >> 3, r = nwg & 7;
  const int xcd = bid & 7, idx = bid >> 3;
  const int swz = (xcd < r ? xcd * (q + 1) : r * (q + 1) + (xcd - r) * q) + idx;
  const int mt = swz / GX, nt = swz % GX;

  // staging geometry: thread covers flat bf16 elems [(i*256+tid)*8, +8)
  const int flat0 = tid * 8;              // LDS elem offset, chunk 0
  const int row0 = flat0 >> 5, kk0 = flat0 & 31;
  const int row1 = 64 + row0;             // chunk 1: flat1 = 2048 + flat0

  const u16* Ab = A + (size_t)(mt * 128) * KD;
  const u16* Bb = BT + (size_t)(nt * 128) * KD;
  const u16* ga0 = Ab + row0 * KD + kk0;
  const u16* ga1 = Ab + row1 * KD + kk0;
  const u16* gb0 = Bb + row0 * KD + kk0;
  const u16* gb1 = Bb + row1 * KD + kk0;
  u16* lA0 = As + flat0;
  u16* lA1 = As + 2048 + flat0;
  u16* lB0 = Bs + flat0;
  u16* lB1 = Bs + 2048 + flat0;

  f32x4_t acc[4][4];
#pragma unroll
  for (int i = 0; i < 4; i++)
#pragma unroll
    for (int j = 0; j < 4; j++)
#pragma unroll
      for (int q2 = 0; q2 < 4; q2++) acc[i][j][q2] = 0.f;

  for (int kt = 0; kt < KD; kt += 32) {
    __syncthreads();   // previous iter's LDS reads done before overwrite
    gl_lds16(ga0 + kt, lA0);
    gl_lds16(ga1 + kt, lA1);
    gl_lds16(gb0 + kt, lB0);
    gl_lds16(gb1 + kt, lB1);
    __syncthreads();   // compiler drains vmcnt(0) before barrier -> LDS valid
    short8_t af[4], bfr[4];
#pragma unroll
    for (int i = 0; i < 4; i++)
      af[i] = *(const short8_t*)(As + (wr * 64 + i * 16 + l15) * 32 + kg);
#pragma unroll
    for (int i = 0; i < 4; i++)
      bfr[i] = *(const short8_t*)(Bs + (wc * 64 + i * 16 + l15) * 32 + kg);
#pragma unroll
    for (int i = 0; i < 4; i++)
#pragma unroll
      for (int j = 0; j < 4; j++)
        acc[i][j] = __builtin_amdgcn_mfma_f32_16x16x32_bf16(af[i], bfr[j], acc[i][j], 0, 0, 0);
  }

  const int rbase = mt * 128 + wr * 64 + (lane >> 4) * 4;
  const int cbase = nt * 128 + wc * 64 + l15;
#pragma unroll
  for (int i = 0; i < 4; i++) {
#pragma unroll
    for (int j = 0; j < 4; j++) {
#pragma unroll
      for (int q2 = 0; q2 < 4; q2++) {
        int rr = rbase + i * 16 + q2;
        int cc = cbase + j * 16;
        if (!GUARD || rr < mvalid) {
          float v = acc[i][j][q2];
          if (HAS_BIAS) v += bias[cc];
          if (OUTBF) Cb[(size_t)rr * ldc + cc] = f2bf(v);
          else       Cf[(size_t)rr * ldc + cc] = v;
        }
      }
    }
  }
}

// ---------------- attention logits: al_s/al_d [NND][4] (bf16 hproj) ----------------

__global__ __launch_bounds__(256) void k_al(const u16* __restrict__ hprojb,
                                            const float* __restrict__ a_src,
                                            const float* __restrict__ a_dst,
                                            float* __restrict__ al_s,
                                            float* __restrict__ al_d) {
  int n = blockIdx.x, t = threadIdx.x;
  ushort4 hq = ((const ushort4*)(hprojb + (size_t)n * DH))[t];
  float4 as = ((const float4*)a_src)[t];
  float4 ad = ((const float4*)a_dst)[t];
  float hx = bf2f(hq.x), hy = bf2f(hq.y), hz = bf2f(hq.z), hw = bf2f(hq.w);
  float ps = hx * as.x + hy * as.y + hz * as.z + hw * as.w;
  float pd = hx * ad.x + hy * ad.y + hz * ad.z + hw * ad.w;
#pragma unroll
  for (int off = 32; off; off >>= 1) {
    ps += __shfl_xor(ps, off);
    pd += __shfl_xor(pd, off);
  }
  if ((t & 63) == 0) {
    int h = t >> 6;
    al_s[n * 4 + h] = ps;
    al_d[n * 4 + h] = pd;
  }
}

// ---------------- segment softmax + weighted aggregation ----------------
// one block per dst node. Wide-gather: threads 0-127 process even edges,
// 128-255 odd edges; each thread owns 8 channels via 16B uint4 loads.
// out = relu(sum(alpha*h[src]) + bias) as bf16.

__global__ __launch_bounds__(256) void k_agg(const u16* __restrict__ hprojb,
                                             const float* __restrict__ al_s,
                                             const float* __restrict__ al_d,
                                             const int* __restrict__ rowp,
                                             const int* __restrict__ colsrc,
                                             const float* __restrict__ bias,
                                             u16* __restrict__ outb) {
  __shared__ int csrc[CHUNK];
  __shared__ float cw[CHUNK * 4];
  __shared__ float smax[4][4];
  __shared__ float sbmax[4];
  __shared__ float comb[128 * 9];
  const int n = blockIdx.x, t = threadIdx.x;
  const int wv = t >> 6, ln = t & 63;
  const int half = t >> 7, u = t & 127;   // u: channel-octet index, 8 ch/thread
  const int head = u >> 5;
  const int beg = rowp[n], end = rowp[n + 1];
  const float4 ad = ((const float4*)al_d)[n];

  // pass A: per-head max of leaky_relu(al_s[src]+al_d[n])
  float m0 = -1e30f, m1 = -1e30f, m2 = -1e30f, m3 = -1e30f;
  for (int e = beg + t; e < end; e += 256) {
    int s = colsrc[e];
    float4 as = ((const float4*)al_s)[s];
    m0 = fmaxf(m0, lrelu(as.x + ad.x));
    m1 = fmaxf(m1, lrelu(as.y + ad.y));
    m2 = fmaxf(m2, lrelu(as.z + ad.z));
    m3 = fmaxf(m3, lrelu(as.w + ad.w));
  }
#pragma unroll
  for (int off = 32; off; off >>= 1) {
    m0 = fmaxf(m0, __shfl_xor(m0, off));
    m1 = fmaxf(m1, __shfl_xor(m1, off));
    m2 = fmaxf(m2, __shfl_xor(m2, off));
    m3 = fmaxf(m3, __shfl_xor(m3, off));
  }
  if (ln == 0) { smax[0][wv] = m0; smax[1][wv] = m1; smax[2][wv] = m2; smax[3][wv] = m3; }
  __syncthreads();
  if (t < 4)
    sbmax[t] = fmaxf(fmaxf(smax[t][0], smax[t][1]), fmaxf(smax[t][2], smax[t][3]));
  __syncthreads();
  const float bm0 = sbmax[0], bm1 = sbmax[1], bm2 = sbmax[2], bm3 = sbmax[3];

  // pass B: chunked accumulate of sum(w*h) and sum(w); 16B loads, 2 edges in flight
  float a0 = 0.f, a1 = 0.f, a2 = 0.f, a3 = 0.f;
  float a4 = 0.f, a5 = 0.f, a6 = 0.f, a7 = 0.f;
  float dsum = 0.f;
  const u16* hrow = hprojb + u * 8;
  for (int cs = beg; cs < end; cs += CHUNK) {
    int m = end - cs; if (m > CHUNK) m = CHUNK;
    __syncthreads();   // protect LDS from previous chunk readers
    if (t < m) {
      int s = colsrc[cs + t];
      csrc[t] = s;
      float4 as = ((const float4*)al_s)[s];
      float4 wv4;
      wv4.x = __expf(lrelu(as.x + ad.x) - bm0);
      wv4.y = __expf(lrelu(as.y + ad.y) - bm1);
      wv4.z = __expf(lrelu(as.z + ad.z) - bm2);
      wv4.w = __expf(lrelu(as.w + ad.w) - bm3);
      ((float4*)cw)[t] = wv4;
    }
    __syncthreads();
    for (int i = half; i < m; i += 2) {
      int s = csrc[i];
      float wgt = cw[i * 4 + head];
      uint4 hv = *(const uint4*)(hrow + (size_t)s * DH);
      a0 += bflo(hv.x) * wgt; a1 += bfhi(hv.x) * wgt;
      a2 += bflo(hv.y) * wgt; a3 += bfhi(hv.y) * wgt;
      a4 += bflo(hv.z) * wgt; a5 += bfhi(hv.z) * wgt;
      a6 += bflo(hv.w) * wgt; a7 += bfhi(hv.w) * wgt;
      dsum += wgt;
    }
  }
  __syncthreads();
  if (half) {
    float* cb = comb + u * 9;
    cb[0] = a0; cb[1] = a1; cb[2] = a2; cb[3] = a3;
    cb[4] = a4; cb[5] = a5; cb[6] = a6; cb[7] = a7;
    cb[8] = dsum;
  }
  __syncthreads();
  if (!half) {
    const float* cb = comb + u * 9;
    a0 += cb[0]; a1 += cb[1]; a2 += cb[2]; a3 += cb[3];
    a4 += cb[4]; a5 += cb[5]; a6 += cb[6]; a7 += cb[7];
    dsum += cb[8];
    const float inv = 1.f / dsum;
    float4 bv0 = ((const float4*)bias)[u * 2];
    float4 bv1 = ((const float4*)bias)[u * 2 + 1];
    float o0 = fmaxf(a0 * inv + bv0.x, 0.f);
    float o1 = fmaxf(a1 * inv + bv0.y, 0.f);
    float o2 = fmaxf(a2 * inv + bv0.z, 0.f);
    float o3 = fmaxf(a3 * inv + bv0.w, 0.f);
    float o4 = fmaxf(a4 * inv + bv1.x, 0.f);
    float o5 = fmaxf(a5 * inv + bv1.y, 0.f);
    float o6 = fmaxf(a6 * inv + bv1.z, 0.f);
    float o7 = fmaxf(a7 * inv + bv1.w, 0.f);
    uint4 ob;
    ob.x = (unsigned)f2bf(o0) | ((unsigned)f2bf(o1) << 16);
    ob.y = (unsigned)f2bf(o2) | ((unsigned)f2bf(o3) << 16);
    ob.z = (unsigned)f2bf(o4) | ((unsigned)f2bf(o5) << 16);
    ob.w = (unsigned)f2bf(o6) | ((unsigned)f2bf(o7) << 16);
    ((uint4*)(outb + (size_t)n * DH))[u] = ob;
  }
}

// ---------------- launcher ----------------

extern "C" void kernel_launch(void* const* d_in, const int* in_sizes, int n_in,
                              void* d_out, int out_size, void* d_ws, size_t ws_size,
                              hipStream_t stream) {
  const float* x   = (const float*)d_in[0];
  const int*   ei  = (const int*)d_in[1];
  const float* W1  = (const float*)d_in[2];
  const float* as1 = (const float*)d_in[3];
  const float* ad1 = (const float*)d_in[4];
  const float* b1  = (const float*)d_in[5];
  const float* W2  = (const float*)d_in[6];
  const float* as2 = (const float*)d_in[7];
  const float* ad2 = (const float*)d_in[8];
  const float* b2  = (const float*)d_in[9];
  const float* Wfc = (const float*)d_in[10];
  const float* bfc = (const float*)d_in[11];
  float* out = (float*)d_out;
  (void)in_sizes; (void)n_in; (void)out_size; (void)ws_size;

  // workspace carve
  char* p = (char*)d_ws;
  auto carve = [&](size_t bytes) -> char* {
    char* r = p; p += (bytes + 255) & ~(size_t)255; return r;
  };
  u16*   xb     = (u16*)  carve((size_t)MP * DIN * 2);
  u16*   w1t    = (u16*)  carve((size_t)DH * DIN * 2);    // [1024][512]
  u16*   w2t    = (u16*)  carve((size_t)DH * DH * 2);     // [1024][1024]
  u16*   wft    = (u16*)  carve((size_t)DOUT * DH * 2);   // [512][1024]
  u16*   hprojb = (u16*)  carve((size_t)MP * DH * 2);     // bf16 projection
  u16*   hb     = (u16*)  carve((size_t)MP * DH * 2);
  u16*   h2b    = (u16*)  carve((size_t)MP * DH * 2);
  float* als    = (float*)carve((size_t)NND * 4 * 4);
  float* ald    = (float*)carve((size_t)NND * 4 * 4);
  int*   indeg  = (int*)  carve((size_t)NND * 4);
  int*   rowp   = (int*)  carve((size_t)(NND + 1) * 4);
  int*   cursor = (int*)  carve((size_t)NND * 4);
  int*   colsrc = (int*)  carve((size_t)NET * 4);

  // prep: zeros, conversions, CSR
  k_prep0<<<((MP - NND) * DH / 8 + 255) / 256, 256, 0, stream>>>(indeg, cursor,
      hb + (size_t)NND * DH, h2b + (size_t)NND * DH);
  k_conv_x<<<(MP * DIN / 4 + 255) / 256, 256, 0, stream>>>(x, xb);
  k_transpose_w<<<dim3(DH / 32, DIN / 32), dim3(32, 8), 0, stream>>>(W1, w1t, DIN, DH);
  k_transpose_w<<<dim3(DH / 32, DH / 32), dim3(32, 8), 0, stream>>>(W2, w2t, DH, DH);
  k_transpose_w<<<dim3(DOUT / 32, DH / 32), dim3(32, 8), 0, stream>>>(Wfc, wft, DH, DOUT);
  k_count<<<(NET + 255) / 256, 256, 0, stream>>>(ei, indeg);
  k_scan<<<1, 1024, 0, stream>>>(indeg, rowp);
  k_fill<<<(NET + 255) / 256, 256, 0, stream>>>(ei, rowp, cursor, colsrc);

  // layer 1
  k_gemm<DIN, 8, false, false, true><<<dim3(DH / 128, MP / 128), 256, 0, stream>>>(xb, w1t, nullptr, hprojb, nullptr, DH, MP);
  k_al<<<NND, 256, 0, stream>>>(hprojb, as1, ad1, als, ald);
  k_agg<<<NND, 256, 0, stream>>>(hprojb, als, ald, rowp, colsrc, b1, hb);

  // layer 2
  k_gemm<DH, 8, false, false, true><<<dim3(DH / 128, MP / 128), 256, 0, stream>>>(hb, w2t, nullptr, hprojb, nullptr, DH, MP);
  k_al<<<NND, 256, 0, stream>>>(hprojb, as2, ad2, als, ald);
  k_agg<<<NND, 256, 0, stream>>>(hprojb, als, ald, rowp, colsrc, b2, h2b);

  // FC
  k_gemm<DH, 4, true, true, false><<<dim3(DOUT / 128, MP / 128), 256, 0, stream>>>(h2b, wft, out, nullptr, bfc, DOUT, NND);
}

// Round 4
// 240.582 us; speedup vs baseline: 1.5803x; 1.0154x over previous
//
#include <hip/hip_runtime.h>

// Problem constants
#define NND 10000      // nodes
#define NED 160000     // edges (before self loops)
#define NET 170000     // edges incl self loops
#define MP  10112      // node rows padded to multiple of 128 (79*128)
#define DH  1024       // H*C hidden width
#define DIN 512
#define DOUT 512
#define SCB 40         // scan blocks: ceil(NND/256)

typedef unsigned short u16;
typedef __attribute__((ext_vector_type(8))) short short8_t;
typedef __attribute__((ext_vector_type(4))) float f32x4_t;

__device__ __forceinline__ u16 f2bf(float f) {
  unsigned u = __float_as_uint(f);
  return (u16)((u + 0x7fffu + ((u >> 16) & 1u)) >> 16);
}
__device__ __forceinline__ float bf2f(u16 b) {
  return __uint_as_float(((unsigned)b) << 16);
}
__device__ __forceinline__ float bflo(unsigned u) { return __uint_as_float(u << 16); }
__device__ __forceinline__ float bfhi(unsigned u) { return __uint_as_float(u & 0xffff0000u); }
__device__ __forceinline__ float lrelu(float v) { return v > 0.f ? v : 0.2f * v; }

// async global->LDS, 16B per lane. LDS dest must be linear (uniform base + lane*16).
__device__ __forceinline__ void gl_lds16(const void* g, void* l) {
  __builtin_amdgcn_global_load_lds(
      (const __attribute__((address_space(1))) unsigned int*)g,
      (__attribute__((address_space(3))) unsigned int*)l, 16, 0, 0);
}

// ---------------- merged prep: zero indeg + pad rows of hb/h2b ----------------

__global__ void k_prep0(int* __restrict__ indeg,
                        u16* __restrict__ hbp, u16* __restrict__ h2bp) {
  int i = blockIdx.x * 256 + threadIdx.x;
  if (i < NND) indeg[i] = 0;
  const uint4 z = make_uint4(0, 0, 0, 0);
  if (i < (MP - NND) * DH / 8) {
    ((uint4*)hbp)[i] = z;
    ((uint4*)h2bp)[i] = z;
  }
}

// x [NND][DIN] f32 -> xb [MP][DIN] bf16 (pad rows zero)
__global__ void k_conv_x(const float* __restrict__ x, u16* __restrict__ xb) {
  int i = blockIdx.x * 256 + threadIdx.x;   // quad index
  const int total = MP * DIN / 4;
  if (i >= total) return;
  float4 v = make_float4(0.f, 0.f, 0.f, 0.f);
  if (i < NND * DIN / 4) v = ((const float4*)x)[i];
  ushort4 o;
  o.x = f2bf(v.x); o.y = f2bf(v.y); o.z = f2bf(v.z); o.w = f2bf(v.w);
  ((ushort4*)xb)[i] = o;
}

// W [K][Nt] f32 -> WT [Nt][K] bf16  (LDS tiled transpose)
__global__ void k_transpose_w(const float* __restrict__ W, u16* __restrict__ WT,
                              int K, int Nt) {
  __shared__ float s[32][33];
  int kt = blockIdx.y * 32, nt = blockIdx.x * 32;
  int tx = threadIdx.x, ty = threadIdx.y;   // (32,8)
#pragma unroll
  for (int i = 0; i < 32; i += 8)
    s[ty + i][tx] = W[(size_t)(kt + ty + i) * Nt + nt + tx];
  __syncthreads();
#pragma unroll
  for (int i = 0; i < 32; i += 8)
    WT[(size_t)(nt + ty + i) * K + kt + tx] = f2bf(s[tx][ty + i]);
}

// ---------------- CSR build ----------------

__global__ void k_count(const int* __restrict__ ei, int* __restrict__ indeg) {
  int e = blockIdx.x * 256 + threadIdx.x;
  if (e >= NET) return;
  int dst = (e < NED) ? ei[NED + e] : (e - NED);
  atomicAdd(&indeg[dst], 1);
}

// 3-stage multi-block scan over indeg -> rowp (exclusive, rowp[0]=0)
__global__ void k_scan1(const int* __restrict__ indeg, int* __restrict__ rowp,
                        int* __restrict__ bsum) {
  __shared__ int ws[4];
  const int b = blockIdx.x, t = threadIdx.x, wv = t >> 6, ln = t & 63;
  const int i = b * 256 + t;
  int v = (i < NND) ? indeg[i] : 0;
  int sc = v;
#pragma unroll
  for (int off = 1; off < 64; off <<= 1) {
    int xx = __shfl_up(sc, off);
    if (ln >= off) sc += xx;
  }
  if (ln == 63) ws[wv] = sc;
  __syncthreads();
  if (t == 0) {
    int a = 0;
#pragma unroll
    for (int k = 0; k < 4; k++) { int tmp = ws[k]; ws[k] = a; a += tmp; }
    bsum[b] = a;
  }
  __syncthreads();
  sc += ws[wv];
  if (i < NND) rowp[i + 1] = sc;   // block-local inclusive
}

__global__ void k_scan2(int* __restrict__ bsum) {   // 1 block, 64 threads
  int t = threadIdx.x;
  int v = (t < SCB) ? bsum[t] : 0;
  int sc = v;
#pragma unroll
  for (int off = 1; off < 64; off <<= 1) {
    int xx = __shfl_up(sc, off);
    if (t >= off) sc += xx;
  }
  if (t < SCB) bsum[t] = sc - v;   // exclusive
}

__global__ void k_scan3(int* __restrict__ rowp, const int* __restrict__ bsum,
                        int* __restrict__ cursor) {
  const int b = blockIdx.x, t = threadIdx.x;
  const int i = b * 256 + t;
  if (i < NND) { rowp[i + 1] += bsum[b]; cursor[i] = 0; }
  if (i == 0) rowp[0] = 0;
}

__global__ void k_fill(const int* __restrict__ ei, const int* __restrict__ rowp,
                       int* __restrict__ cursor, int* __restrict__ colsrc) {
  int e = blockIdx.x * 256 + threadIdx.x;
  if (e >= NET) return;
  int src, dst;
  if (e < NED) { src = ei[e]; dst = ei[NED + e]; }
  else         { src = dst = e - NED; }
  int pos = rowp[dst] + atomicAdd(&cursor[dst], 1);
  colsrc[pos] = src;
}

// ---------------- GEMM: C[M][ldc] = A[M][KD] * BT[Nt][KD]^T (+bias) ----------------
// bf16 inputs, fp32 accum. Output bf16 (OUTBF) or fp32. 128x128 tile, BK=32,
// 4 waves, 16x16x32 MFMA, global_load_lds width-16 staging, XCD-chunked swizzle.

template <int KD, int GX, bool HAS_BIAS, bool GUARD, bool OUTBF>
__global__ __launch_bounds__(256) void k_gemm(const u16* __restrict__ A,
                                              const u16* __restrict__ BT,
                                              float* __restrict__ Cf,
                                              u16* __restrict__ Cb,
                                              const float* __restrict__ bias,
                                              int ldc, int mvalid) {
  __shared__ __align__(16) u16 As[128 * 32];
  __shared__ __align__(16) u16 Bs[128 * 32];
  const int tid = threadIdx.x;
  const int lane = tid & 63;
  const int w = tid >> 6;
  const int wr = w >> 1, wc = w & 1;
  const int l15 = lane & 15;
  const int kg = (lane >> 4) * 8;

  // XCD-chunked bijective swizzle (m204)
  const int nwg = GX * gridDim.y;
  const int bid = blockIdx.y * GX + blockIdx.x;
  const int q = nwg >> 3, r = nwg & 7;
  const int xcd = bid & 7, idx = bid >> 3;
  const int swz = (xcd < r ? xcd * (q + 1) : r * (q + 1) + (xcd - r) * q) + idx;
  const int mt = swz / GX, nt = swz % GX;

  const int flat0 = tid * 8;
  const int row0 = flat0 >> 5, kk0 = flat0 & 31;
  const int row1 = 64 + row0;

  const u16* Ab = A + (size_t)(mt * 128) * KD;
  const u16* Bb = BT + (size_t)(nt * 128) * KD;
  const u16* ga0 = Ab + row0 * KD + kk0;
  const u16* ga1 = Ab + row1 * KD + kk0;
  const u16* gb0 = Bb + row0 * KD + kk0;
  const u16* gb1 = Bb + row1 * KD + kk0;
  u16* lA0 = As + flat0;
  u16* lA1 = As + 2048 + flat0;
  u16* lB0 = Bs + flat0;
  u16* lB1 = Bs + 2048 + flat0;

  f32x4_t acc[4][4];
#pragma unroll
  for (int i = 0; i < 4; i++)
#pragma unroll
    for (int j = 0; j < 4; j++)
#pragma unroll
      for (int q2 = 0; q2 < 4; q2++) acc[i][j][q2] = 0.f;

  for (int kt = 0; kt < KD; kt += 32) {
    __syncthreads();
    gl_lds16(ga0 + kt, lA0);
    gl_lds16(ga1 + kt, lA1);
    gl_lds16(gb0 + kt, lB0);
    gl_lds16(gb1 + kt, lB1);
    __syncthreads();
    short8_t af[4], bfr[4];
#pragma unroll
    for (int i = 0; i < 4; i++)
      af[i] = *(const short8_t*)(As + (wr * 64 + i * 16 + l15) * 32 + kg);
#pragma unroll
    for (int i = 0; i < 4; i++)
      bfr[i] = *(const short8_t*)(Bs + (wc * 64 + i * 16 + l15) * 32 + kg);
#pragma unroll
    for (int i = 0; i < 4; i++)
#pragma unroll
      for (int j = 0; j < 4; j++)
        acc[i][j] = __builtin_amdgcn_mfma_f32_16x16x32_bf16(af[i], bfr[j], acc[i][j], 0, 0, 0);
  }

  const int rbase = mt * 128 + wr * 64 + (lane >> 4) * 4;
  const int cbase = nt * 128 + wc * 64 + l15;
#pragma unroll
  for (int i = 0; i < 4; i++) {
#pragma unroll
    for (int j = 0; j < 4; j++) {
#pragma unroll
      for (int q2 = 0; q2 < 4; q2++) {
        int rr = rbase + i * 16 + q2;
        int cc = cbase + j * 16;
        if (!GUARD || rr < mvalid) {
          float v = acc[i][j][q2];
          if (HAS_BIAS) v += bias[cc];
          if (OUTBF) Cb[(size_t)rr * ldc + cc] = f2bf(v);
          else       Cf[(size_t)rr * ldc + cc] = v;
        }
      }
    }
  }
}

// ---------------- attention logits: al_s/al_d [NND][4] (bf16 hproj) ----------------

__global__ __launch_bounds__(256) void k_al(const u16* __restrict__ hprojb,
                                            const float* __restrict__ a_src,
                                            const float* __restrict__ a_dst,
                                            float* __restrict__ al_s,
                                            float* __restrict__ al_d) {
  int n = blockIdx.x, t = threadIdx.x;
  ushort4 hq = ((const ushort4*)(hprojb + (size_t)n * DH))[t];
  float4 as = ((const float4*)a_src)[t];
  float4 ad = ((const float4*)a_dst)[t];
  float hx = bf2f(hq.x), hy = bf2f(hq.y), hz = bf2f(hq.z), hw = bf2f(hq.w);
  float ps = hx * as.x + hy * as.y + hz * as.z + hw * as.w;
  float pd = hx * ad.x + hy * ad.y + hz * ad.z + hw * ad.w;
#pragma unroll
  for (int off = 32; off; off >>= 1) {
    ps += __shfl_xor(ps, off);
    pd += __shfl_xor(pd, off);
  }
  if ((t & 63) == 0) {
    int h = t >> 6;
    al_s[n * 4 + h] = ps;
    al_d[n * 4 + h] = pd;
  }
}

// ---------------- edge softmax: normalized alpha [NET][4] fp32 ----------------
// one wave per dst node: max -> w=exp(..) -> dsum -> alpha = w/dsum

__global__ __launch_bounds__(64) void k_alpha(const float* __restrict__ al_s,
                                              const float* __restrict__ al_d,
                                              const int* __restrict__ rowp,
                                              const int* __restrict__ colsrc,
                                              float* __restrict__ alpha) {
  const int n = blockIdx.x, ln = threadIdx.x;
  const int beg = rowp[n], end = rowp[n + 1];
  const float4 ad = ((const float4*)al_d)[n];

  float m0 = -1e30f, m1 = -1e30f, m2 = -1e30f, m3 = -1e30f;
  for (int e = beg + ln; e < end; e += 64) {
    int s = colsrc[e];
    float4 as = ((const float4*)al_s)[s];
    m0 = fmaxf(m0, lrelu(as.x + ad.x));
    m1 = fmaxf(m1, lrelu(as.y + ad.y));
    m2 = fmaxf(m2, lrelu(as.z + ad.z));
    m3 = fmaxf(m3, lrelu(as.w + ad.w));
  }
#pragma unroll
  for (int off = 32; off; off >>= 1) {
    m0 = fmaxf(m0, __shfl_xor(m0, off));
    m1 = fmaxf(m1, __shfl_xor(m1, off));
    m2 = fmaxf(m2, __shfl_xor(m2, off));
    m3 = fmaxf(m3, __shfl_xor(m3, off));
  }

  float d0 = 0.f, d1 = 0.f, d2 = 0.f, d3 = 0.f;
  for (int e = beg + ln; e < end; e += 64) {
    int s = colsrc[e];
    float4 as = ((const float4*)al_s)[s];
    float4 wv;
    wv.x = __expf(lrelu(as.x + ad.x) - m0);
    wv.y = __expf(lrelu(as.y + ad.y) - m1);
    wv.z = __expf(lrelu(as.z + ad.z) - m2);
    wv.w = __expf(lrelu(as.w + ad.w) - m3);
    ((float4*)alpha)[e] = wv;
    d0 += wv.x; d1 += wv.y; d2 += wv.z; d3 += wv.w;
  }
#pragma unroll
  for (int off = 32; off; off >>= 1) {
    d0 += __shfl_xor(d0, off);
    d1 += __shfl_xor(d1, off);
    d2 += __shfl_xor(d2, off);
    d3 += __shfl_xor(d3, off);
  }
  const float i0 = 1.f / d0, i1 = 1.f / d1, i2 = 1.f / d2, i3 = 1.f / d3;
  for (int e = beg + ln; e < end; e += 64) {
    float4 wv = ((const float4*)alpha)[e];
    wv.x *= i0; wv.y *= i1; wv.z *= i2; wv.w *= i3;
    ((float4*)alpha)[e] = wv;
  }
}

// ---------------- weighted gather: one wave per (dst, channel-half) ----------------
// out[n, half*512 .. +512) = relu(sum_e alpha[e]*h[src_e]) + bias, bf16.
// Channel-halving keeps the gather footprint at 10 MB per dispatch phase (L2 locality).

__global__ __launch_bounds__(64) void k_agg2(const u16* __restrict__ hprojb,
                                             const float* __restrict__ alpha,
                                             const int* __restrict__ rowp,
                                             const int* __restrict__ colsrc,
                                             const float* __restrict__ bias,
                                             u16* __restrict__ outb) {
  const int n = blockIdx.x, half = blockIdx.y, ln = threadIdx.x;
  const int beg = rowp[n], end = rowp[n + 1];
  const int hsel = 2 * half + (ln >> 5);          // head index for this lane's 8 ch
  const u16* hbase = hprojb + half * 512 + ln * 8;

  float a0 = 0.f, a1 = 0.f, a2 = 0.f, a3 = 0.f;
  float a4 = 0.f, a5 = 0.f, a6 = 0.f, a7 = 0.f;
  int e = beg;
  for (; e + 1 < end; e += 2) {
    int s0 = colsrc[e], s1 = colsrc[e + 1];
    float w0 = alpha[e * 4 + hsel];
    float w1 = alpha[(e + 1) * 4 + hsel];
    uint4 h0 = *(const uint4*)(hbase + (size_t)s0 * DH);
    uint4 h1 = *(const uint4*)(hbase + (size_t)s1 * DH);
    a0 += bflo(h0.x) * w0; a1 += bfhi(h0.x) * w0;
    a2 += bflo(h0.y) * w0; a3 += bfhi(h0.y) * w0;
    a4 += bflo(h0.z) * w0; a5 += bfhi(h0.z) * w0;
    a6 += bflo(h0.w) * w0; a7 += bfhi(h0.w) * w0;
    a0 += bflo(h1.x) * w1; a1 += bfhi(h1.x) * w1;
    a2 += bflo(h1.y) * w1; a3 += bfhi(h1.y) * w1;
    a4 += bflo(h1.z) * w1; a5 += bfhi(h1.z) * w1;
    a6 += bflo(h1.w) * w1; a7 += bfhi(h1.w) * w1;
  }
  if (e < end) {
    int s0 = colsrc[e];
    float w0 = alpha[e * 4 + hsel];
    uint4 h0 = *(const uint4*)(hbase + (size_t)s0 * DH);
    a0 += bflo(h0.x) * w0; a1 += bfhi(h0.x) * w0;
    a2 += bflo(h0.y) * w0; a3 += bfhi(h0.y) * w0;
    a4 += bflo(h0.z) * w0; a5 += bfhi(h0.z) * w0;
    a6 += bflo(h0.w) * w0; a7 += bfhi(h0.w) * w0;
  }

  const float4 bv0 = *(const float4*)(bias + half * 512 + ln * 8);
  const float4 bv1 = *(const float4*)(bias + half * 512 + ln * 8 + 4);
  float o0 = fmaxf(a0 + bv0.x, 0.f), o1 = fmaxf(a1 + bv0.y, 0.f);
  float o2 = fmaxf(a2 + bv0.z, 0.f), o3 = fmaxf(a3 + bv0.w, 0.f);
  float o4 = fmaxf(a4 + bv1.x, 0.f), o5 = fmaxf(a5 + bv1.y, 0.f);
  float o6 = fmaxf(a6 + bv1.z, 0.f), o7 = fmaxf(a7 + bv1.w, 0.f);
  uint4 ob;
  ob.x = (unsigned)f2bf(o0) | ((unsigned)f2bf(o1) << 16);
  ob.y = (unsigned)f2bf(o2) | ((unsigned)f2bf(o3) << 16);
  ob.z = (unsigned)f2bf(o4) | ((unsigned)f2bf(o5) << 16);
  ob.w = (unsigned)f2bf(o6) | ((unsigned)f2bf(o7) << 16);
  *(uint4*)(outb + (size_t)n * DH + half * 512 + ln * 8) = ob;
}

// ---------------- launcher ----------------

extern "C" void kernel_launch(void* const* d_in, const int* in_sizes, int n_in,
                              void* d_out, int out_size, void* d_ws, size_t ws_size,
                              hipStream_t stream) {
  const float* x   = (const float*)d_in[0];
  const int*   ei  = (const int*)d_in[1];
  const float* W1  = (const float*)d_in[2];
  const float* as1 = (const float*)d_in[3];
  const float* ad1 = (const float*)d_in[4];
  const float* b1  = (const float*)d_in[5];
  const float* W2  = (const float*)d_in[6];
  const float* as2 = (const float*)d_in[7];
  const float* ad2 = (const float*)d_in[8];
  const float* b2  = (const float*)d_in[9];
  const float* Wfc = (const float*)d_in[10];
  const float* bfc = (const float*)d_in[11];
  float* out = (float*)d_out;
  (void)in_sizes; (void)n_in; (void)out_size; (void)ws_size;

  // workspace carve
  char* p = (char*)d_ws;
  auto carve = [&](size_t bytes) -> char* {
    char* r = p; p += (bytes + 255) & ~(size_t)255; return r;
  };
  u16*   xb     = (u16*)  carve((size_t)MP * DIN * 2);
  u16*   w1t    = (u16*)  carve((size_t)DH * DIN * 2);
  u16*   w2t    = (u16*)  carve((size_t)DH * DH * 2);
  u16*   wft    = (u16*)  carve((size_t)DOUT * DH * 2);
  u16*   hprojb = (u16*)  carve((size_t)MP * DH * 2);
  u16*   hb     = (u16*)  carve((size_t)MP * DH * 2);
  u16*   h2b    = (u16*)  carve((size_t)MP * DH * 2);
  float* als    = (float*)carve((size_t)NND * 4 * 4);
  float* ald    = (float*)carve((size_t)NND * 4 * 4);
  float* alpha  = (float*)carve((size_t)NET * 4 * 4);
  int*   indeg  = (int*)  carve((size_t)NND * 4);
  int*   rowp   = (int*)  carve((size_t)(NND + 1) * 4);
  int*   cursor = (int*)  carve((size_t)NND * 4);
  int*   colsrc = (int*)  carve((size_t)NET * 4);
  int*   bsum   = (int*)  carve((size_t)SCB * 4);

  // prep + CSR
  k_prep0<<<((MP - NND) * DH / 8 + 255) / 256, 256, 0, stream>>>(indeg,
      hb + (size_t)NND * DH, h2b + (size_t)NND * DH);
  k_conv_x<<<(MP * DIN / 4 + 255) / 256, 256, 0, stream>>>(x, xb);
  k_transpose_w<<<dim3(DH / 32, DIN / 32), dim3(32, 8), 0, stream>>>(W1, w1t, DIN, DH);
  k_transpose_w<<<dim3(DH / 32, DH / 32), dim3(32, 8), 0, stream>>>(W2, w2t, DH, DH);
  k_transpose_w<<<dim3(DOUT / 32, DH / 32), dim3(32, 8), 0, stream>>>(Wfc, wft, DH, DOUT);
  k_count<<<(NET + 255) / 256, 256, 0, stream>>>(ei, indeg);
  k_scan1<<<SCB, 256, 0, stream>>>(indeg, rowp, bsum);
  k_scan2<<<1, 64, 0, stream>>>(bsum);
  k_scan3<<<SCB, 256, 0, stream>>>(rowp, bsum, cursor);
  k_fill<<<(NET + 255) / 256, 256, 0, stream>>>(ei, rowp, cursor, colsrc);

  // layer 1
  k_gemm<DIN, 8, false, false, true><<<dim3(DH / 128, MP / 128), 256, 0, stream>>>(xb, w1t, nullptr, hprojb, nullptr, DH, MP);
  k_al<<<NND, 256, 0, stream>>>(hprojb, as1, ad1, als, ald);
  k_alpha<<<NND, 64, 0, stream>>>(als, ald, rowp, colsrc, alpha);
  k_agg2<<<dim3(NND, 2), 64, 0, stream>>>(hprojb, alpha, rowp, colsrc, b1, hb);

  // layer 2
  k_gemm<DH, 8, false, false, true><<<dim3(DH / 128, MP / 128), 256, 0, stream>>>(hb, w2t, nullptr, hprojb, nullptr, DH, MP);
  k_al<<<NND, 256, 0, stream>>>(hprojb, as2, ad2, als, ald);
  k_alpha<<<NND, 64, 0, stream>>>(als, ald, rowp, colsrc, alpha);
  k_agg2<<<dim3(NND, 2), 64, 0, stream>>>(hprojb, alpha, rowp, colsrc, b2, h2b);

  // FC
  k_gemm<DH, 4, true, true, false><<<dim3(DOUT / 128, MP / 128), 256, 0, stream>>>(h2b, wft, out, nullptr, bfc, DOUT, NND);
}